// Round 1
// baseline (262.615 us; speedup 1.0000x reference)
//
#include <hip/hip_runtime.h>
#include <hip/hip_bf16.h>

// DenseContrastiveLossV2 on MI355X.
// Structure:
//  K1 gather_norm: F_bf16[8192][256] = normalized sampled features -> d_ws (4 MB)
//  K2 supcon: per 32-row block, sweep all 128 column tiles (64 cols each) once:
//     negative-label tiles -> per-row neg_sum = sum exp(dot/t - 2)   (m=2 is exact:
//     log_prob is shift-invariant in the max, and diag dot/t == 2 is the true max)
//     positive-label tiles -> sum_{j!=i} (l - log(exp(l)+neg_sum)), l = dot/t - 2
//     loss contribution = -sum / (pos_count * 8192), atomicAdd into d_out.
// Symmetry of S = F F^T + tile-uniform masks make the MFMA layout choice
// correctness-invariant (any transposition yields the same value per slot).

namespace {

constexpr int kC = 256;
constexpr int kHW = 96 * 96;
constexpr int kT = 32;
constexpr int kV = 256;
constexpr int kM = kT * kV;    // 8192 vectors
constexpr int kCT = kM / 64;   // 128 column tiles of 64
constexpr int kNW = 8;         // waves per supcon block
constexpr float kInvTemp = 2.0f;  // 1 / 0.5

typedef __attribute__((ext_vector_type(8))) short short8;  // 8 bf16 = 4 VGPRs
typedef __attribute__((ext_vector_type(4))) float f32x4;

__device__ inline unsigned short f2bf(float x) {
  __hip_bfloat16 h = __float2bfloat16(x);
  return __builtin_bit_cast(unsigned short, h);
}

}  // namespace

// ---------------- Kernel 1: gather + L2 normalize -> bf16 ----------------
__global__ __launch_bounds__(256) void gather_norm_kernel(
    const float* __restrict__ feat, const int* __restrict__ binds,
    const int* __restrict__ sinds, unsigned short* __restrict__ F) {
  const int vec = (int)((blockIdx.x * 256u + threadIdx.x) >> 6);  // 0..8191
  const int lane = threadIdx.x & 63;
  const int t = vec >> 8;  // vec / V
  const int b = binds[t];
  const int p = sinds[vec];
  const float* base = feat + (size_t)(b * kC) * kHW + p;
  const int c0 = lane * 4;
  float v0 = base[(size_t)(c0 + 0) * kHW];
  float v1 = base[(size_t)(c0 + 1) * kHW];
  float v2 = base[(size_t)(c0 + 2) * kHW];
  float v3 = base[(size_t)(c0 + 3) * kHW];
  float ss = v0 * v0 + v1 * v1 + v2 * v2 + v3 * v3;
#pragma unroll
  for (int m = 1; m < 64; m <<= 1) ss += __shfl_xor(ss, m, 64);
  const float inv = 1.0f / fmaxf(sqrtf(ss), 1e-12f);
  ushort4 o;
  o.x = f2bf(v0 * inv);
  o.y = f2bf(v1 * inv);
  o.z = f2bf(v2 * inv);
  o.w = f2bf(v3 * inv);
  *reinterpret_cast<ushort4*>(F + (size_t)vec * kC + c0) = o;
}

// ---------------- Kernel 2: SupCon loss ----------------
__device__ inline void compute_tile(const short* __restrict__ Fs, int ct,
                                    int l16, int q, const short8 (&af)[2][8],
                                    f32x4 (&acc)[2][4]) {
  const f32x4 zero = {0.f, 0.f, 0.f, 0.f};
#pragma unroll
  for (int rg = 0; rg < 2; ++rg)
#pragma unroll
    for (int cg = 0; cg < 4; ++cg) acc[rg][cg] = zero;
#pragma unroll
  for (int cg = 0; cg < 4; ++cg) {
    const short* bb = Fs + (ct * 64 + cg * 16 + l16) * kC + q * 8;
#pragma unroll
    for (int ks = 0; ks < 8; ++ks) {
      short8 bf = *reinterpret_cast<const short8*>(bb + ks * 32);
      acc[0][cg] =
          __builtin_amdgcn_mfma_f32_16x16x32_bf16(af[0][ks], bf, acc[0][cg], 0, 0, 0);
      acc[1][cg] =
          __builtin_amdgcn_mfma_f32_16x16x32_bf16(af[1][ks], bf, acc[1][cg], 0, 0, 0);
    }
  }
}

__global__ __launch_bounds__(kNW * 64) void supcon_kernel(
    const unsigned short* __restrict__ F, const int* __restrict__ labels,
    float* __restrict__ out) {
  const int tid = (int)threadIdx.x;
  const int w = tid >> 6;
  const int lane = tid & 63;
  const int q = lane >> 4;
  const int l16 = lane & 15;
  const int row0 = (int)blockIdx.x * 32;

  __shared__ int s_lab[kT];
  __shared__ float s_ns[kNW][32];
  __shared__ float s_nsf[32];
  __shared__ float s_pos[kNW];

  if (tid < kT) s_lab[tid] = labels[tid];
  __syncthreads();
  const int labi = s_lab[row0 >> 8];

  const short* Fs = reinterpret_cast<const short*>(F);

  // Preload A fragments: this block's 32 rows, full K=256, kept in VGPRs.
  short8 af[2][8];
#pragma unroll
  for (int rg = 0; rg < 2; ++rg)
#pragma unroll
    for (int ks = 0; ks < 8; ++ks)
      af[rg][ks] = *reinterpret_cast<const short8*>(
          Fs + (row0 + rg * 16 + l16) * kC + ks * 32 + q * 8);

  // ---- Sweep 1: negative tiles -> per-row sum of exp(dot/t - 2) ----
  float sacc[2][4] = {{0.f, 0.f, 0.f, 0.f}, {0.f, 0.f, 0.f, 0.f}};
  for (int ct = w; ct < kCT; ct += kNW) {
    if (s_lab[ct >> 2] == labi) continue;
    f32x4 acc[2][4];
    compute_tile(Fs, ct, l16, q, af, acc);
#pragma unroll
    for (int rg = 0; rg < 2; ++rg)
#pragma unroll
      for (int r = 0; r < 4; ++r) {
        sacc[rg][r] += __expf(kInvTemp * acc[rg][0][r] - 2.f) +
                       __expf(kInvTemp * acc[rg][1][r] - 2.f) +
                       __expf(kInvTemp * acc[rg][2][r] - 2.f) +
                       __expf(kInvTemp * acc[rg][3][r] - 2.f);
      }
  }
  // Reduce across the 16 column-lanes; rows live at (q*4 + r) within group.
#pragma unroll
  for (int rg = 0; rg < 2; ++rg)
#pragma unroll
    for (int r = 0; r < 4; ++r) {
      float v = sacc[rg][r];
      v += __shfl_xor(v, 1, 64);
      v += __shfl_xor(v, 2, 64);
      v += __shfl_xor(v, 4, 64);
      v += __shfl_xor(v, 8, 64);
      if (l16 == 0) s_ns[w][rg * 16 + q * 4 + r] = v;
    }
  __syncthreads();
  if (tid < 32) {
    float v = 0.f;
#pragma unroll
    for (int ww = 0; ww < kNW; ++ww) v += s_ns[ww][tid];
    s_nsf[tid] = v;
  }
  __syncthreads();
  float nsl[2][4];
#pragma unroll
  for (int rg = 0; rg < 2; ++rg)
#pragma unroll
    for (int r = 0; r < 4; ++r) nsl[rg][r] = s_nsf[rg * 16 + q * 4 + r];

  // ---- Sweep 2: positive tiles -> sum_{j!=i} l - log(exp(l) + neg_sum) ----
  float pos = 0.f;
  for (int ct = w; ct < kCT; ct += kNW) {
    if (s_lab[ct >> 2] != labi) continue;
    f32x4 acc[2][4];
    compute_tile(Fs, ct, l16, q, af, acc);
#pragma unroll
    for (int rg = 0; rg < 2; ++rg)
#pragma unroll
      for (int cg = 0; cg < 4; ++cg)
#pragma unroll
        for (int r = 0; r < 4; ++r) {
          float d = kInvTemp * acc[rg][cg][r] - 2.f;
          int i = row0 + rg * 16 + q * 4 + r;
          int j = ct * 64 + cg * 16 + l16;
          if (i != j) pos += d - __logf(__expf(d) + nsl[rg][r]);
        }
  }
#pragma unroll
  for (int m = 1; m < 64; m <<= 1) pos += __shfl_xor(pos, m, 64);
  if (lane == 0) s_pos[w] = pos;
  __syncthreads();
  if (tid == 0) {
    float tot = 0.f;
#pragma unroll
    for (int ww = 0; ww < kNW; ++ww) tot += s_pos[ww];
    int matches = 0;
    for (int t = 0; t < kT; ++t) matches += (s_lab[t] == labi) ? 1 : 0;
    const float cnt = (float)(matches * kV - 1);  // >= 255, no eps needed
    atomicAdd(out, -tot / (cnt * (float)kM));
  }
}

extern "C" void kernel_launch(void* const* d_in, const int* in_sizes, int n_in,
                              void* d_out, int out_size, void* d_ws,
                              size_t ws_size, hipStream_t stream) {
  const float* feat = (const float*)d_in[0];
  const int* binds = (const int*)d_in[1];
  const int* sinds = (const int*)d_in[2];   // harness passes integers as int32
  const int* labels = (const int*)d_in[3];
  float* out = (float*)d_out;
  unsigned short* F = (unsigned short*)d_ws;  // 8192*256 bf16 = 4 MB

  hipMemsetAsync(d_out, 0, sizeof(float) * out_size, stream);
  gather_norm_kernel<<<kM / 4, 256, 0, stream>>>(feat, binds, sinds, F);
  supcon_kernel<<<kM / 32, kNW * 64, 0, stream>>>(F, labels, out);
}

// Round 2
// 199.787 us; speedup vs baseline: 1.3145x; 1.3145x over previous
//
#include <hip/hip_runtime.h>
#include <hip/hip_bf16.h>

// DenseContrastiveLossV2 on MI355X — round 2.
// K0 k_gather : block (b,c) loads feat row coalesced to LDS, scatters samples
//               from LDS, writes FT[c][vec] bf16 (coalesced).     FT: 4 MB
// K1 k_norm   : transpose+L2-normalize -> F[vec][c] bf16.          F: 4 MB
// K2 k_neg    : 64 rows x 2048-col chunk per block; B tiles staged via
//               global_load_lds (16B, XOR-swizzled LDS layout); per-row
//               sum exp(2*dot-2) over negative-label tiles -> atomicAdd ns[row]
// K3 k_pos    : matching-label tiles only; sum (d - log(exp d + ns[i])),
//               atomicAdd scalar loss.   (shift m=2 cancels exactly in logprob)

namespace {

constexpr int kC = 256;
constexpr int kHW = 96 * 96;   // 9216
constexpr int kT = 32;
constexpr int kV = 256;
constexpr int kM = kT * kV;    // 8192

typedef __attribute__((ext_vector_type(8))) short short8;  // 8 bf16
typedef __attribute__((ext_vector_type(4))) float f32x4;

__device__ inline unsigned short f2bf(float x) {
  __hip_bfloat16 h = __float2bfloat16(x);
  return __builtin_bit_cast(unsigned short, h);
}
__device__ inline float bf2f(unsigned short u) {
  unsigned int v = ((unsigned int)u) << 16;
  return __builtin_bit_cast(float, v);
}
__device__ inline void load_lds16(const unsigned short* g, unsigned short* l) {
  __builtin_amdgcn_global_load_lds(
      (const __attribute__((address_space(1))) void*)g,
      (__attribute__((address_space(3))) void*)l, 16, 0, 0);
}

}  // namespace

// ---------------- K0: gather (coalesced row staging) ----------------
__global__ __launch_bounds__(256) void k_gather(
    const float* __restrict__ feat, const int* __restrict__ binds,
    const int* __restrict__ sinds, unsigned short* __restrict__ FT) {
  const int b = (int)blockIdx.x;   // 0..7
  const int c = (int)blockIdx.y;   // 0..255
  __shared__ alignas(16) float row[kHW];
  __shared__ int s_match[kT + 1];
  if (threadIdx.x == 0) {
    int cnt = 0;
    for (int t = 0; t < kT; ++t)
      if (binds[t] == b) s_match[1 + cnt++] = t;
    s_match[0] = cnt;
  }
  __syncthreads();
  const int cnt = s_match[0];
  if (cnt == 0) return;
  const float4* src4 = (const float4*)(feat + ((size_t)b * kC + c) * kHW);
  for (int i = (int)threadIdx.x; i < kHW / 4; i += 256)
    ((float4*)row)[i] = src4[i];
  __syncthreads();
  unsigned short* dst = FT + (size_t)c * kM;
  for (int mi = 1; mi <= cnt; ++mi) {
    const int t = s_match[mi];
    const int p = sinds[t * kV + threadIdx.x];
    dst[t * kV + threadIdx.x] = f2bf(row[p]);
  }
}

// ---------------- K1: transpose + normalize ----------------
__global__ __launch_bounds__(256) void k_norm(
    const unsigned short* __restrict__ FT, unsigned short* __restrict__ F) {
  constexpr int PAD = 40;  // 32 vecs + 8 pad (80 B rows: breaks bank aliasing)
  const int v0 = (int)blockIdx.x * 32;
  __shared__ alignas(16) unsigned short tile[kC][PAD];
  __shared__ float part[8][32];
  __shared__ float s_inv[32];
  const int tid = (int)threadIdx.x;
  {
    const int p4 = tid & 3, cb = tid >> 2;  // 4x16B per 64B c-row
    for (int c = cb; c < kC; c += 64) {
      int4 d = *(const int4*)(FT + (size_t)c * kM + v0 + p4 * 8);
      *(int4*)&tile[c][p4 * 8] = d;
    }
  }
  __syncthreads();
  {
    const int v = tid & 31, oct = tid >> 5;
    float ss = 0.f;
    for (int c = oct * 32; c < oct * 32 + 32; ++c) {
      float x = bf2f(tile[c][v]);
      ss += x * x;
    }
    part[oct][v] = ss;
  }
  __syncthreads();
  if (tid < 32) {
    float ss = 0.f;
#pragma unroll
    for (int o = 0; o < 8; ++o) ss += part[o][tid];
    s_inv[tid] = 1.0f / fmaxf(sqrtf(ss), 1e-12f);
  }
  __syncthreads();
#pragma unroll
  for (int p = 0; p < 4; ++p) {
    const int chunk = p * 256 + tid;
    const int v = chunk >> 5, c0 = (chunk & 31) << 3;
    const float inv = s_inv[v];
    alignas(16) unsigned short o[8];
#pragma unroll
    for (int k = 0; k < 8; ++k) o[k] = f2bf(bf2f(tile[c0 + k][v]) * inv);
    *(int4*)(F + (size_t)(v0 + v) * kC + c0) = *(const int4*)o;
  }
}

// ---------------- K2: negative sweep -> ns[row] ----------------
__global__ __launch_bounds__(256, 2) void k_neg(
    const unsigned short* __restrict__ F, const int* __restrict__ labels,
    float* __restrict__ ns) {
  const int tid = (int)threadIdx.x;
  const int w = tid >> 6, lane = tid & 63, q = lane >> 4, l16 = lane & 15;
  const int row0 = (int)blockIdx.y * 64;
  const int cx = (int)blockIdx.x;  // 0..3
  __shared__ alignas(16) unsigned short Bt[64 * kC];  // 32 KB, swizzled
  __shared__ int s_lab[kT];
  __shared__ float s_red[4][64];
  if (tid < kT) s_lab[tid] = labels[tid];
  __syncthreads();
  const int labr = s_lab[row0 >> 8];

  short8 af[4][8];
#pragma unroll
  for (int rg = 0; rg < 4; ++rg)
#pragma unroll
    for (int ks = 0; ks < 8; ++ks)
      af[rg][ks] = *(const short8*)((const short*)F +
                                    (size_t)(row0 + rg * 16 + l16) * kC +
                                    ks * 32 + q * 8);

  const int j2 = w * 16 + l16;
  const unsigned short* bcol = Bt + j2 * kC;
  int bofs[8];
#pragma unroll
  for (int ks = 0; ks < 8; ++ks)
    bofs[ks] = ((ks * 4 + q) ^ (j2 & 31)) << 3;

  float sacc[4][4] = {};
  for (int ct = cx * 32; ct < cx * 32 + 32; ++ct) {
    if (s_lab[ct >> 2] == labr) continue;  // block-uniform skip
    __syncthreads();                       // everyone done with Bt
#pragma unroll
    for (int i = 0; i < 8; ++i) {
      const int n = w * 512 + i * 64 + lane;
      const int j = n >> 5;                      // col 0..63
      const int m = (lane & 31) ^ (j & 31);      // swizzled 16B k-chunk
      load_lds16(F + ((size_t)(ct * 64 + j) << 8) + m * 8,
                 Bt + (size_t)(w * 512 + i * 64) * 8);
    }
    __syncthreads();  // staging drained
    f32x4 acc[4];
#pragma unroll
    for (int rg = 0; rg < 4; ++rg) acc[rg] = (f32x4){0.f, 0.f, 0.f, 0.f};
#pragma unroll
    for (int ks = 0; ks < 8; ++ks) {
      short8 bf = *(const short8*)(bcol + bofs[ks]);
#pragma unroll
      for (int rg = 0; rg < 4; ++rg)
        acc[rg] = __builtin_amdgcn_mfma_f32_16x16x32_bf16(af[rg][ks], bf,
                                                          acc[rg], 0, 0, 0);
    }
#pragma unroll
    for (int rg = 0; rg < 4; ++rg)
#pragma unroll
      for (int r = 0; r < 4; ++r)
        sacc[rg][r] += __expf(fmaf(acc[rg][r], 2.f, -2.f));
  }
#pragma unroll
  for (int rg = 0; rg < 4; ++rg)
#pragma unroll
    for (int r = 0; r < 4; ++r) {
      float v = sacc[rg][r];
      v += __shfl_xor(v, 1, 64);
      v += __shfl_xor(v, 2, 64);
      v += __shfl_xor(v, 4, 64);
      v += __shfl_xor(v, 8, 64);
      if (l16 == 0) s_red[w][rg * 16 + q * 4 + r] = v;
    }
  __syncthreads();
  if (tid < 64) {
    float v = s_red[0][tid] + s_red[1][tid] + s_red[2][tid] + s_red[3][tid];
    atomicAdd(&ns[row0 + tid], v);
  }
}

// ---------------- K3: positive sweep -> loss ----------------
__global__ __launch_bounds__(256, 2) void k_pos(
    const unsigned short* __restrict__ F, const int* __restrict__ labels,
    const float* __restrict__ ns, float* __restrict__ out) {
  const int tid = (int)threadIdx.x;
  const int w = tid >> 6, lane = tid & 63, q = lane >> 4, l16 = lane & 15;
  const int row0 = (int)blockIdx.y * 64;
  const int tcol = (int)blockIdx.x;  // 0..31
  __shared__ alignas(16) unsigned short Bt[64 * kC];
  __shared__ int s_lab[kT];
  __shared__ float s_pos[4];
  if (tid < kT) s_lab[tid] = labels[tid];
  __syncthreads();
  const int labr = s_lab[row0 >> 8];
  if (s_lab[tcol] != labr) return;  // block-uniform

  short8 af[4][8];
#pragma unroll
  for (int rg = 0; rg < 4; ++rg)
#pragma unroll
    for (int ks = 0; ks < 8; ++ks)
      af[rg][ks] = *(const short8*)((const short*)F +
                                    (size_t)(row0 + rg * 16 + l16) * kC +
                                    ks * 32 + q * 8);
  const int j2 = w * 16 + l16;
  const unsigned short* bcol = Bt + j2 * kC;
  int bofs[8];
#pragma unroll
  for (int ks = 0; ks < 8; ++ks)
    bofs[ks] = ((ks * 4 + q) ^ (j2 & 31)) << 3;

  float nsv[4][4];
#pragma unroll
  for (int rg = 0; rg < 4; ++rg)
#pragma unroll
    for (int r = 0; r < 4; ++r)
      nsv[rg][r] = ns[row0 + rg * 16 + q * 4 + r];

  float pos = 0.f;
  for (int ti = 0; ti < 4; ++ti) {
    const int ct = tcol * 4 + ti;
    __syncthreads();
#pragma unroll
    for (int i = 0; i < 8; ++i) {
      const int n = w * 512 + i * 64 + lane;
      const int j = n >> 5;
      const int m = (lane & 31) ^ (j & 31);
      load_lds16(F + ((size_t)(ct * 64 + j) << 8) + m * 8,
                 Bt + (size_t)(w * 512 + i * 64) * 8);
    }
    __syncthreads();
    f32x4 acc[4];
#pragma unroll
    for (int rg = 0; rg < 4; ++rg) acc[rg] = (f32x4){0.f, 0.f, 0.f, 0.f};
#pragma unroll
    for (int ks = 0; ks < 8; ++ks) {
      short8 bf = *(const short8*)(bcol + bofs[ks]);
#pragma unroll
      for (int rg = 0; rg < 4; ++rg)
        acc[rg] = __builtin_amdgcn_mfma_f32_16x16x32_bf16(af[rg][ks], bf,
                                                          acc[rg], 0, 0, 0);
    }
    const int jcol = ct * 64 + j2;
#pragma unroll
    for (int rg = 0; rg < 4; ++rg)
#pragma unroll
      for (int r = 0; r < 4; ++r) {
        const int i = row0 + rg * 16 + q * 4 + r;
        if (i != jcol) {
          float d = fmaf(acc[rg][r], 2.f, -2.f);
          pos += d - __logf(__expf(d) + nsv[rg][r]);
        }
      }
  }
#pragma unroll
  for (int m = 1; m < 64; m <<= 1) pos += __shfl_xor(pos, m, 64);
  if (lane == 0) s_pos[w] = pos;
  __syncthreads();
  if (tid == 0) {
    float tot = s_pos[0] + s_pos[1] + s_pos[2] + s_pos[3];
    int matches = 0;
    for (int t = 0; t < kT; ++t) matches += (s_lab[t] == labr) ? 1 : 0;
    const float cnt = (float)(matches * kV - 1);
    atomicAdd(out, -tot / (cnt * (float)kM));
  }
}

extern "C" void kernel_launch(void* const* d_in, const int* in_sizes, int n_in,
                              void* d_out, int out_size, void* d_ws,
                              size_t ws_size, hipStream_t stream) {
  const float* feat = (const float*)d_in[0];
  const int* binds = (const int*)d_in[1];
  const int* sinds = (const int*)d_in[2];
  const int* labels = (const int*)d_in[3];
  float* out = (float*)d_out;
  unsigned short* FT = (unsigned short*)d_ws;            // 4 MB  [256][8192]
  unsigned short* F = FT + (size_t)kC * kM;              // 4 MB  [8192][256]
  float* ns = (float*)(F + (size_t)kM * kC);             // 32 KB [8192]

  hipMemsetAsync(d_out, 0, sizeof(float) * out_size, stream);
  hipMemsetAsync(ns, 0, sizeof(float) * kM, stream);
  k_gather<<<dim3(8, kC), 256, 0, stream>>>(feat, binds, sinds, FT);
  k_norm<<<kM / 32, 256, 0, stream>>>(FT, F);
  k_neg<<<dim3(4, kM / 64), 256, 0, stream>>>(F, labels, ns);
  k_pos<<<dim3(kT, kM / 64), 256, 0, stream>>>(F, labels, ns, out);
}